// Round 2
// baseline (251.656 us; speedup 1.0000x reference)
//
#include <hip/hip_runtime.h>

// Problem constants (B=16, C=128, H=W=64, N=4096, M=256, K=9, OUT=128)
#define NB   16
#define NC   128
#define NN   4096
#define NM   256
#define NK   9
#define NO   128

typedef __attribute__((ext_vector_type(8))) short bf16x8;
typedef __attribute__((ext_vector_type(4))) float f32x4;

__device__ __constant__ int d_grid16[16] = {0,4,8,13,17,21,25,29,34,38,42,46,50,55,59,63};

__device__ inline unsigned short bf16_rne(float v) {
    unsigned u = __float_as_uint(v);
    return (unsigned short)((u + 0x7FFFu + ((u >> 16) & 1u)) >> 16);
}

// Merge two ascending sorted 16-lists, keep lowest 16 ascending (branch-free).
// s := sorted16( lowest16( s ∪ q ) );  q must be ascending sorted.
__device__ inline void merge16(unsigned* s, const unsigned* q) {
    unsigned r[16];
    #pragma unroll
    for (int i = 0; i < 16; ++i) r[i] = min(s[i], q[15 - i]);   // bitonic low-half
    #pragma unroll
    for (int d = 8; d >= 1; d >>= 1)
        #pragma unroll
        for (int i = 0; i < 16; ++i)
            if (!(i & d)) { unsigned a = r[i], b2 = r[i + d]; r[i] = min(a, b2); r[i + d] = max(a, b2); }
    #pragma unroll
    for (int i = 0; i < 16; ++i) s[i] = r[i];
}

// ---------------------------------------------------------------------------
// K_PREP: unchanged (reduction loops unrolled 16; add-chain order preserved).
__global__ __launch_bounds__(256) void k_prep(const float* __restrict__ x,
                                              const float* __restrict__ w,
                                              float* __restrict__ xsT,
                                              unsigned short* __restrict__ xsTh,
                                              unsigned short* __restrict__ xsTl,
                                              unsigned short* __restrict__ Wth,
                                              unsigned short* __restrict__ Wtl,
                                              float* __restrict__ n2g,
                                              float* __restrict__ m2) {
    __shared__ float tile[16 * 260];
    int bx = blockIdx.x, t = threadIdx.x;
    if (bx < 128) {
        int b = bx >> 3, c0 = (bx & 7) * 16;
        int m = t;
        int pix = d_grid16[m >> 4] * 64 + d_grid16[m & 15];
        #pragma unroll
        for (int cc = 0; cc < 16; ++cc)
            tile[cc * 260 + m] = x[((size_t)b * NC + c0 + cc) * NN + pix];
        __syncthreads();
        #pragma unroll
        for (int e = 0; e < 4; ++e) {
            float fv[4];
            fv[0] = tile[(4 * e + 0) * 260 + m];
            fv[1] = tile[(4 * e + 1) * 260 + m];
            fv[2] = tile[(4 * e + 2) * 260 + m];
            fv[3] = tile[(4 * e + 3) * 260 + m];
            size_t base = ((size_t)b * NM + m) * NC + c0 + 4 * e;
            *(float4*)&xsT[base] = make_float4(fv[0], fv[1], fv[2], fv[3]);
            unsigned short h4[4], l4[4];
            #pragma unroll
            for (int e2 = 0; e2 < 4; ++e2) {
                unsigned short h = bf16_rne(fv[e2]);
                h4[e2] = h;
                l4[e2] = bf16_rne(fv[e2] - __uint_as_float(((unsigned)h) << 16));
            }
            *(ushort4*)&xsTh[base] = make_ushort4(h4[0], h4[1], h4[2], h4[3]);
            *(ushort4*)&xsTl[base] = make_ushort4(l4[0], l4[1], l4[2], l4[3]);
        }
    } else if (bx < 704) {
        int f = (bx - 128) * 256 + t;               // < 147456 = 1152*128
        int ko = f >> 7, c = f & 127;
        int o = ko & 127, k = ko >> 7;
        float v = w[(size_t)o * 1152 + c * 9 + k];
        unsigned short h = bf16_rne(v);
        Wth[f] = h;
        Wtl[f] = bf16_rne(v - __uint_as_float(((unsigned)h) << 16));
    } else if (bx < 960) {
        #pragma clang fp contract(off)
        int i = bx - 704;                           // 256 blocks: b x 16 n-chunks
        int b = i >> 4, n = (i & 15) * 256 + t;
        const float* p = x + (size_t)b * NC * NN + n;
        float a = 0.f;
        #pragma unroll 16
        for (int c = 0; c < NC; ++c) { float v = p[(size_t)c * NN]; a = __fadd_rn(a, __fmul_rn(v, v)); }
        n2g[(size_t)b * NN + n] = a;
    } else {
        #pragma clang fp contract(off)
        int b = bx - 960;                           // 16 blocks: t = m
        int pix = d_grid16[t >> 4] * 64 + d_grid16[t & 15];
        const float* p = x + (size_t)b * NC * NN + pix;
        float a = 0.f;
        #pragma unroll 16
        for (int c = 0; c < NC; ++c) { float v = p[(size_t)c * NN]; a = __fadd_rn(a, __fmul_rn(v, v)); }
        m2[b * NM + t] = a;
    }
}

// ---------------------------------------------------------------------------
// K_G (MFMA): G[b][m][k][o] = sum_c xs[m][c] * W[k,o][c], split-bf16 3-term.
__global__ __launch_bounds__(256) void k_g(const unsigned short* __restrict__ xsTh,
                                           const unsigned short* __restrict__ xsTl,
                                           const unsigned short* __restrict__ Wth,
                                           const unsigned short* __restrict__ Wtl,
                                           float* __restrict__ G) {
    int id = blockIdx.x;
    int b = id & 15, r = id >> 4;                   // r < 36
    int kk = r % 9, mt = r / 9;
    int t = threadIdx.x;
    int w = t >> 6, lane = t & 63;
    int lr = lane & 15, quad = lane >> 4;
    int m = b * NM + mt * 64 + w * 16 + lr;
    const unsigned short* aph = xsTh + (size_t)m * NC;
    const unsigned short* apl = xsTl + (size_t)m * NC;
    f32x4 acc[8];
    #pragma unroll
    for (int j = 0; j < 8; ++j) acc[j] = (f32x4){0.f, 0.f, 0.f, 0.f};
    #pragma unroll
    for (int kb = 0; kb < 4; ++kb) {
        int co = kb * 32 + quad * 8;
        bf16x8 Ah = *(const bf16x8*)&aph[co];
        bf16x8 Al = *(const bf16x8*)&apl[co];
        #pragma unroll
        for (int j = 0; j < 8; ++j) {
            size_t wrow = ((size_t)kk * 128 + 16 * j + lr) * NC + co;
            bf16x8 Bh = *(const bf16x8*)&Wth[wrow];
            bf16x8 Bl = *(const bf16x8*)&Wtl[wrow];
            acc[j] = __builtin_amdgcn_mfma_f32_16x16x32_bf16(Ah, Bh, acc[j], 0, 0, 0);
            acc[j] = __builtin_amdgcn_mfma_f32_16x16x32_bf16(Al, Bh, acc[j], 0, 0, 0);
            acc[j] = __builtin_amdgcn_mfma_f32_16x16x32_bf16(Ah, Bl, acc[j], 0, 0, 0);
        }
    }
    int mrow = b * NM + mt * 64 + w * 16 + quad * 4;
    #pragma unroll
    for (int j = 0; j < 8; ++j)
        #pragma unroll
        for (int r2 = 0; r2 < 4; ++r2)
            G[((size_t)(mrow + r2)) * 1152 + kk * 128 + 16 * j + lr] = acc[j][r2];
}

// ---------------------------------------------------------------------------
// K_SELREF v3: 32 tokens/block (2048 blocks), swapped-operand MFMA with
// A-fragments reused across both 16-token halves; per-lane keys carry the
// sample index in the low 8 bits; sorted 16-deep candidate lists maintained
// through branch-free bitonic merges (no rescan, no atomics, no keysl).
__global__ __launch_bounds__(256, 4) void k_selref(const float* __restrict__ x,
                                                   const unsigned short* __restrict__ xsTh,
                                                   const unsigned short* __restrict__ xsTl,
                                                   const float* __restrict__ xsT,
                                                   const float* __restrict__ m2,
                                                   const float* __restrict__ n2g,
                                                   int* __restrict__ idx) {
    #pragma clang fp contract(off)
    __shared__ __align__(16) float x1l[32 * 132];            // 16896 B  [tok][c]
    __shared__ __align__(16) unsigned short xhp[32 * 136];   //  8704 B  bf16-hi plane
    __shared__ __align__(16) unsigned short xlp[32 * 136];   //  8704 B  bf16-lo plane
    __shared__ __align__(16) unsigned mrg[32 * 17 * 2];      //  4352 B  wl(4096) ∪ pairs(4352)
    __shared__ unsigned short candl[32 * 16];                //  1024 B
    __shared__ float m2l[256];                               //  1024 B
    __shared__ float n2l[32];                                //   128 B
    unsigned* wl = mrg;                                      // [wave][lr][16] u32
    unsigned long long* pairs = (unsigned long long*)mrg;    // [tok][17] u64

    int b = blockIdx.x & 15, n0 = (blockIdx.x >> 4) * 32;
    int t = threadIdx.x;
    int w = t >> 6, lane = t & 63;
    int lr = lane & 15, quad = lane >> 4;

    m2l[t] = m2[b * NM + t];
    if (t < 32) n2l[t] = n2g[(size_t)b * NN + n0 + t];

    // ---- stage x1l [tok][c] (transpose during write) ----
    #pragma unroll
    for (int it = 0; it < 4; ++it) {
        int f4 = it * 256 + t;                  // < 1024
        int c = f4 >> 3, nn4 = (f4 & 7) * 4;
        float4 v = *(const float4*)&x[((size_t)b * NC + c) * NN + n0 + nn4];
        x1l[(nn4 + 0) * 132 + c] = v.x;
        x1l[(nn4 + 1) * 132 + c] = v.y;
        x1l[(nn4 + 2) * 132 + c] = v.z;
        x1l[(nn4 + 3) * 132 + c] = v.w;
    }
    __syncthreads();

    // ---- cooperative split-bf16 conversion of token planes (16 elems/thread) ----
    {
        int tok = t >> 3, c0 = (t & 7) * 16;
        #pragma unroll
        for (int g = 0; g < 4; ++g) {
            float4 v = *(const float4*)&x1l[tok * 132 + c0 + 4 * g];
            float vf[4] = {v.x, v.y, v.z, v.w};
            unsigned short h4[4], l4[4];
            #pragma unroll
            for (int e = 0; e < 4; ++e) {
                unsigned short h = bf16_rne(vf[e]);
                h4[e] = h;
                l4[e] = bf16_rne(vf[e] - __uint_as_float(((unsigned)h) << 16));
            }
            *(ushort4*)&xhp[tok * 136 + c0 + 4 * g] = make_ushort4(h4[0], h4[1], h4[2], h4[3]);
            *(ushort4*)&xlp[tok * 136 + c0 + 4 * g] = make_ushort4(l4[0], l4[1], l4[2], l4[3]);
        }
    }
    __syncthreads();

    // ---- MFMA: A = samples (global planes, batch-issued), B = tokens (LDS) ----
    // acc[h][j]: h = token half (cols 16h..16h+15), j = m-subtile.
    // Per-acc term order (AhBh, AhBl, AlBh) identical to prior versions.
    f32x4 acc[2][4];
    #pragma unroll
    for (int i = 0; i < 2; ++i)
        #pragma unroll
        for (int j = 0; j < 4; ++j) acc[i][j] = (f32x4){0.f, 0.f, 0.f, 0.f};
    int mbase = w * 64;
    #pragma unroll
    for (int kb = 0; kb < 4; ++kb) {
        int co = kb * 32 + quad * 8;
        bf16x8 Bh0 = *(const bf16x8*)&xhp[lr * 136 + co];
        bf16x8 Bl0 = *(const bf16x8*)&xlp[lr * 136 + co];
        bf16x8 Bh1 = *(const bf16x8*)&xhp[(16 + lr) * 136 + co];
        bf16x8 Bl1 = *(const bf16x8*)&xlp[(16 + lr) * 136 + co];
        bf16x8 Ah[4], Al[4];
        #pragma unroll
        for (int j = 0; j < 4; ++j) {               // batch-issue 8 global loads
            size_t arow = ((size_t)(b * NM + mbase + 16 * j + lr)) * NC + co;
            Ah[j] = *(const bf16x8*)&xsTh[arow];
            Al[j] = *(const bf16x8*)&xsTl[arow];
        }
        #pragma unroll
        for (int j = 0; j < 4; ++j) {
            acc[0][j] = __builtin_amdgcn_mfma_f32_16x16x32_bf16(Ah[j], Bh0, acc[0][j], 0, 0, 0);
            acc[0][j] = __builtin_amdgcn_mfma_f32_16x16x32_bf16(Ah[j], Bl0, acc[0][j], 0, 0, 0);
            acc[0][j] = __builtin_amdgcn_mfma_f32_16x16x32_bf16(Al[j], Bh0, acc[0][j], 0, 0, 0);
            acc[1][j] = __builtin_amdgcn_mfma_f32_16x16x32_bf16(Ah[j], Bh1, acc[1][j], 0, 0, 0);
            acc[1][j] = __builtin_amdgcn_mfma_f32_16x16x32_bf16(Ah[j], Bl1, acc[1][j], 0, 0, 0);
            acc[1][j] = __builtin_amdgcn_mfma_f32_16x16x32_bf16(Al[j], Bh1, acc[1][j], 0, 0, 0);
        }
    }

    // ---- per-half selection: sorted top-16 with index-carrying keys ----
    #pragma unroll
    for (int h = 0; h < 2; ++h) {
        unsigned s16v[16];
        #pragma unroll
        for (int j = 0; j < 4; ++j)
            #pragma unroll
            for (int r = 0; r < 4; ++r) {
                int m = mbase + 16 * j + quad * 4 + r;
                float key = fmaf(-2.f, acc[h][j][r], m2l[m]);
                unsigned u = __float_as_uint(key);
                u = (u & 0x80000000u) ? ~u : (u | 0x80000000u);
                s16v[4 * j + r] = (u & 0xFFFFFF00u) | (unsigned)m;
            }
        #define CE(i,jx) { unsigned a_ = s16v[i], b_ = s16v[jx]; s16v[i] = min(a_, b_); s16v[jx] = max(a_, b_); }
        // sort8 [0..7]
        CE(0,1) CE(2,3) CE(0,2) CE(1,3) CE(1,2)
        CE(4,5) CE(6,7) CE(4,6) CE(5,7) CE(5,6)
        CE(0,4) CE(2,6) CE(2,4) CE(1,5) CE(3,7) CE(3,5) CE(1,2) CE(3,4) CE(5,6)
        // sort8 [8..15]
        CE(8,9) CE(10,11) CE(8,10) CE(9,11) CE(9,10)
        CE(12,13) CE(14,15) CE(12,14) CE(13,15) CE(13,14)
        CE(8,12) CE(10,14) CE(10,12) CE(9,13) CE(11,15) CE(11,13) CE(9,10) CE(11,12) CE(13,14)
        // odd-even merge 8+8
        CE(0,8) CE(4,12) CE(4,8) CE(2,10) CE(6,14) CE(6,10) CE(2,4) CE(6,8) CE(10,12)
        CE(1,9) CE(5,13) CE(5,9) CE(3,11) CE(7,15) CE(7,11) CE(3,5) CE(7,9) CE(11,13)
        CE(1,2) CE(3,4) CE(5,6) CE(7,8) CE(9,10) CE(11,12) CE(13,14)
        #undef CE

        // butterfly across the 4 quads (token lr lives in lanes lr+16q)
        #pragma unroll
        for (int d = 16; d <= 32; d <<= 1) {
            unsigned q[16];
            #pragma unroll
            for (int i = 0; i < 16; ++i) q[i] = (unsigned)__shfl_xor((int)s16v[i], d, 64);
            merge16(s16v, q);
        }

        // cross-wave: publish once, merge other 3 waves' sorted lists
        if (quad == 0) {
            #pragma unroll
            for (int ii = 0; ii < 4; ++ii)
                *(uint4*)&wl[(w * 16 + lr) * 16 + 4 * ii] =
                    make_uint4(s16v[4*ii], s16v[4*ii+1], s16v[4*ii+2], s16v[4*ii+3]);
        }
        __syncthreads();
        #pragma unroll
        for (int p = 1; p < 4; ++p) {
            int pw = (w + p) & 3;
            unsigned q[16];
            #pragma unroll
            for (int i = 0; i < 16; ++i) q[i] = wl[(pw * 16 + lr) * 16 + i];
            merge16(s16v, q);
        }
        if (w == 0 && quad == 0) {
            unsigned* c32 = (unsigned*)candl;
            #pragma unroll
            for (int i = 0; i < 16; i += 2)
                c32[(16 * h + lr) * 8 + (i >> 1)] =
                    (s16v[i] & 255u) | ((s16v[i + 1] & 255u) << 16);
        }
        __syncthreads();   // protects wl reuse (h=0) / precedes pairs aliasing (h=1)
    }

    // ---- ref: np-bit-exact re-rank (32 tokens x 8 lanes x 2 slots) ----
    {
        int tok = t >> 3, q8 = t & 7;
        float n2 = n2l[tok];
        int mym[2];
        unsigned long long myp[2];
        #pragma unroll
        for (int s = 0; s < 2; ++s) {
            int m = candl[tok * 16 + q8 + 8 * s];
            mym[s] = m;
            const float* xt = xsT + ((size_t)(b * NM + m)) * NC;
            float dot = 0.f;
            for (int c4 = 0; c4 < 32; ++c4) {   // sequential in-order: np order
                float4 xv = *(const float4*)&x1l[tok * 132 + 4 * c4];
                float4 sv = *(const float4*)&xt[4 * c4];
                dot = __fadd_rn(dot, __fmul_rn(xv.x, sv.x));
                dot = __fadd_rn(dot, __fmul_rn(xv.y, sv.y));
                dot = __fadd_rn(dot, __fmul_rn(xv.z, sv.z));
                dot = __fadd_rn(dot, __fmul_rn(xv.w, sv.w));
            }
            float key = __fsub_rn(__fadd_rn(n2, m2l[m]), __fmul_rn(2.f, dot));
            unsigned u = __float_as_uint(key);
            u = (u & 0x80000000u) ? ~u : (u | 0x80000000u);
            myp[s] = ((unsigned long long)u << 32) | (unsigned)m;
            pairs[tok * 17 + q8 + 8 * s] = myp[s];
        }
        __syncthreads();
        unsigned long long pl[16];
        #pragma unroll
        for (int l2 = 0; l2 < 16; ++l2) pl[l2] = pairs[tok * 17 + l2];
        size_t obase = (size_t)(b * NN + n0 + tok) * NK;
        #pragma unroll
        for (int s = 0; s < 2; ++s) {
            int rank = 0;
            #pragma unroll
            for (int l2 = 0; l2 < 16; ++l2) rank += (pl[l2] < myp[s]);
            if (rank < 9) idx[obase + rank] = mym[s];
        }
    }
}

// ---------------------------------------------------------------------------
// K_OUT: out[b][o][n] = bias[o] + sum_k G[b][idx[b,n,k]][k][o]
__global__ __launch_bounds__(256) void k_out(const float* __restrict__ G,
                                             const int* __restrict__ idx,
                                             const float* __restrict__ bias,
                                             float* __restrict__ out) {
    __shared__ float S[64 * 129];
    __shared__ int   idxl[576];
    __shared__ float biasl[128];
    int b = blockIdx.x & 15, n0 = (blockIdx.x >> 4) * 64;
    int t = threadIdx.x;
    if (t < 128) biasl[t] = bias[t];
    for (int f = t; f < 576; f += 256) idxl[f] = idx[(size_t)(b * NN + n0) * NK + f];
    __syncthreads();
    int o = t & 127, half = t >> 7;
    for (int p = 0; p < 32; ++p) {
        int n = p * 2 + half;
        float a = biasl[o];
        #pragma unroll
        for (int k = 0; k < 9; ++k) {
            int m = idxl[n * 9 + k];
            a += G[(((size_t)(b * NM + m)) * NK + k) * 128 + o];
        }
        S[n * 129 + o] = a;
    }
    __syncthreads();
    int nn = t & 63, ob = t >> 6;
    for (int p = 0; p < 32; ++p) {
        int o2 = p * 4 + ob;
        out[((size_t)(b * NO + o2)) * NN + n0 + nn] = S[nn * 129 + o2];
    }
}

// ---------------------------------------------------------------------------
extern "C" void kernel_launch(void* const* d_in, const int* in_sizes, int n_in,
                              void* d_out, int out_size, void* d_ws, size_t ws_size,
                              hipStream_t stream) {
    const float* x    = (const float*)d_in[0];   // (16,128,64,64)
    const float* w    = (const float*)d_in[1];   // (128,128,9)
    const float* bias = (const float*)d_in[2];   // (128,)
    float* out = (float*)d_out;

    float* ws   = (float*)d_ws;
    float* m2   = ws;                            // 4096
    float* n2g  = ws + 4096;                     // 65536
    float* xsT  = ws + 69632;                    // 524288
    float* G    = ws + 593920;                   // 4718592
    int*   idx  = (int*)(ws + 5312512);          // 589824
    unsigned short* xsTh = (unsigned short*)(ws + 5902336);  // 524288 u16
    unsigned short* xsTl = (unsigned short*)(ws + 6164480);  // 524288 u16
    unsigned short* Wth  = (unsigned short*)(ws + 6426624);  // 147456 u16
    unsigned short* Wtl  = (unsigned short*)(ws + 6500352);  // 147456 u16

    k_prep  <<<dim3(976),  dim3(256), 0, stream>>>(x, w, xsT, xsTh, xsTl, Wth, Wtl, n2g, m2);
    k_g     <<<dim3(576),  dim3(256), 0, stream>>>(xsTh, xsTl, Wth, Wtl, G);
    k_selref<<<dim3(2048), dim3(256), 0, stream>>>(x, xsTh, xsTl, xsT, m2, n2g, idx);
    k_out   <<<dim3(1024), dim3(256), 0, stream>>>(G, idx, bias, out);
}

// Round 3
// 232.417 us; speedup vs baseline: 1.0828x; 1.0828x over previous
//
#include <hip/hip_runtime.h>

// Problem constants (B=16, C=128, H=W=64, N=4096, M=256, K=9, OUT=128)
#define NB   16
#define NC   128
#define NN   4096
#define NM   256
#define NK   9
#define NO   128

typedef __attribute__((ext_vector_type(8))) short bf16x8;
typedef __attribute__((ext_vector_type(4))) float f32x4;

__device__ __constant__ int d_grid16[16] = {0,4,8,13,17,21,25,29,34,38,42,46,50,55,59,63};

__device__ inline unsigned short bf16_rne(float v) {
    unsigned u = __float_as_uint(v);
    return (unsigned short)((u + 0x7FFFu + ((u >> 16) & 1u)) >> 16);
}

// Merge two ascending sorted 16-lists, keep lowest 16 ascending (branch-free).
// s := sorted16( lowest16( s ∪ q ) );  q must be ascending sorted.
__device__ inline void merge16(unsigned* s, const unsigned* q) {
    unsigned r[16];
    #pragma unroll
    for (int i = 0; i < 16; ++i) r[i] = min(s[i], q[15 - i]);   // bitonic low-half
    #pragma unroll
    for (int d = 8; d >= 1; d >>= 1)
        #pragma unroll
        for (int i = 0; i < 16; ++i)
            if (!(i & d)) { unsigned a = r[i], b2 = r[i + d]; r[i] = min(a, b2); r[i + d] = max(a, b2); }
    #pragma unroll
    for (int i = 0; i < 16; ++i) s[i] = r[i];
}

// ---------------------------------------------------------------------------
// K_PREP: unchanged (reduction loops unrolled 16; add-chain order preserved).
__global__ __launch_bounds__(256) void k_prep(const float* __restrict__ x,
                                              const float* __restrict__ w,
                                              float* __restrict__ xsT,
                                              unsigned short* __restrict__ xsTh,
                                              unsigned short* __restrict__ xsTl,
                                              unsigned short* __restrict__ Wth,
                                              unsigned short* __restrict__ Wtl,
                                              float* __restrict__ n2g,
                                              float* __restrict__ m2) {
    __shared__ float tile[16 * 260];
    int bx = blockIdx.x, t = threadIdx.x;
    if (bx < 128) {
        int b = bx >> 3, c0 = (bx & 7) * 16;
        int m = t;
        int pix = d_grid16[m >> 4] * 64 + d_grid16[m & 15];
        #pragma unroll
        for (int cc = 0; cc < 16; ++cc)
            tile[cc * 260 + m] = x[((size_t)b * NC + c0 + cc) * NN + pix];
        __syncthreads();
        #pragma unroll
        for (int e = 0; e < 4; ++e) {
            float fv[4];
            fv[0] = tile[(4 * e + 0) * 260 + m];
            fv[1] = tile[(4 * e + 1) * 260 + m];
            fv[2] = tile[(4 * e + 2) * 260 + m];
            fv[3] = tile[(4 * e + 3) * 260 + m];
            size_t base = ((size_t)b * NM + m) * NC + c0 + 4 * e;
            *(float4*)&xsT[base] = make_float4(fv[0], fv[1], fv[2], fv[3]);
            unsigned short h4[4], l4[4];
            #pragma unroll
            for (int e2 = 0; e2 < 4; ++e2) {
                unsigned short h = bf16_rne(fv[e2]);
                h4[e2] = h;
                l4[e2] = bf16_rne(fv[e2] - __uint_as_float(((unsigned)h) << 16));
            }
            *(ushort4*)&xsTh[base] = make_ushort4(h4[0], h4[1], h4[2], h4[3]);
            *(ushort4*)&xsTl[base] = make_ushort4(l4[0], l4[1], l4[2], l4[3]);
        }
    } else if (bx < 704) {
        int f = (bx - 128) * 256 + t;               // < 147456 = 1152*128
        int ko = f >> 7, c = f & 127;
        int o = ko & 127, k = ko >> 7;
        float v = w[(size_t)o * 1152 + c * 9 + k];
        unsigned short h = bf16_rne(v);
        Wth[f] = h;
        Wtl[f] = bf16_rne(v - __uint_as_float(((unsigned)h) << 16));
    } else if (bx < 960) {
        #pragma clang fp contract(off)
        int i = bx - 704;                           // 256 blocks: b x 16 n-chunks
        int b = i >> 4, n = (i & 15) * 256 + t;
        const float* p = x + (size_t)b * NC * NN + n;
        float a = 0.f;
        #pragma unroll 16
        for (int c = 0; c < NC; ++c) { float v = p[(size_t)c * NN]; a = __fadd_rn(a, __fmul_rn(v, v)); }
        n2g[(size_t)b * NN + n] = a;
    } else {
        #pragma clang fp contract(off)
        int b = bx - 960;                           // 16 blocks: t = m
        int pix = d_grid16[t >> 4] * 64 + d_grid16[t & 15];
        const float* p = x + (size_t)b * NC * NN + pix;
        float a = 0.f;
        #pragma unroll 16
        for (int c = 0; c < NC; ++c) { float v = p[(size_t)c * NN]; a = __fadd_rn(a, __fmul_rn(v, v)); }
        m2[b * NM + t] = a;
    }
}

// ---------------------------------------------------------------------------
// K_G (MFMA): G[b][m][k][o] = sum_c xs[m][c] * W[k,o][c], split-bf16 3-term.
__global__ __launch_bounds__(256) void k_g(const unsigned short* __restrict__ xsTh,
                                           const unsigned short* __restrict__ xsTl,
                                           const unsigned short* __restrict__ Wth,
                                           const unsigned short* __restrict__ Wtl,
                                           float* __restrict__ G) {
    int id = blockIdx.x;
    int b = id & 15, r = id >> 4;                   // r < 36
    int kk = r % 9, mt = r / 9;
    int t = threadIdx.x;
    int w = t >> 6, lane = t & 63;
    int lr = lane & 15, quad = lane >> 4;
    int m = b * NM + mt * 64 + w * 16 + lr;
    const unsigned short* aph = xsTh + (size_t)m * NC;
    const unsigned short* apl = xsTl + (size_t)m * NC;
    f32x4 acc[8];
    #pragma unroll
    for (int j = 0; j < 8; ++j) acc[j] = (f32x4){0.f, 0.f, 0.f, 0.f};
    #pragma unroll
    for (int kb = 0; kb < 4; ++kb) {
        int co = kb * 32 + quad * 8;
        bf16x8 Ah = *(const bf16x8*)&aph[co];
        bf16x8 Al = *(const bf16x8*)&apl[co];
        #pragma unroll
        for (int j = 0; j < 8; ++j) {
            size_t wrow = ((size_t)kk * 128 + 16 * j + lr) * NC + co;
            bf16x8 Bh = *(const bf16x8*)&Wth[wrow];
            bf16x8 Bl = *(const bf16x8*)&Wtl[wrow];
            acc[j] = __builtin_amdgcn_mfma_f32_16x16x32_bf16(Ah, Bh, acc[j], 0, 0, 0);
            acc[j] = __builtin_amdgcn_mfma_f32_16x16x32_bf16(Al, Bh, acc[j], 0, 0, 0);
            acc[j] = __builtin_amdgcn_mfma_f32_16x16x32_bf16(Ah, Bl, acc[j], 0, 0, 0);
        }
    }
    int mrow = b * NM + mt * 64 + w * 16 + quad * 4;
    #pragma unroll
    for (int j = 0; j < 8; ++j)
        #pragma unroll
        for (int r2 = 0; r2 < 4; ++r2)
            G[((size_t)(mrow + r2)) * 1152 + kk * 128 + 16 * j + lr] = acc[j][r2];
}

// ---------------------------------------------------------------------------
// K_SELREF v4: identical algorithm to v3 (32 tokens/block, swapped-operand
// MFMA, index-carrying keys, sorted top-16 via bitonic merges) but with the
// register budget relaxed: __launch_bounds__(256,2) instead of (256,4).
// v3's (256,4) made the compiler allocate 64 arch-VGPRs and spill the sort
// arrays to scratch (WRITE_SIZE 2.3 -> 41.5 MB). LDS (40 KB) still allows
// 4 blocks/CU if the allocation lands <= 128 regs.
__global__ __launch_bounds__(256, 2) void k_selref(const float* __restrict__ x,
                                                   const unsigned short* __restrict__ xsTh,
                                                   const unsigned short* __restrict__ xsTl,
                                                   const float* __restrict__ xsT,
                                                   const float* __restrict__ m2,
                                                   const float* __restrict__ n2g,
                                                   int* __restrict__ idx) {
    #pragma clang fp contract(off)
    __shared__ __align__(16) float x1l[32 * 132];            // 16896 B  [tok][c]
    __shared__ __align__(16) unsigned short xhp[32 * 136];   //  8704 B  bf16-hi plane
    __shared__ __align__(16) unsigned short xlp[32 * 136];   //  8704 B  bf16-lo plane
    __shared__ __align__(16) unsigned mrg[32 * 17 * 2];      //  4352 B  wl(4096) ∪ pairs(4352)
    __shared__ unsigned short candl[32 * 16];                //  1024 B
    __shared__ float m2l[256];                               //  1024 B
    __shared__ float n2l[32];                                //   128 B
    unsigned* wl = mrg;                                      // [wave][lr][16] u32
    unsigned long long* pairs = (unsigned long long*)mrg;    // [tok][17] u64

    int b = blockIdx.x & 15, n0 = (blockIdx.x >> 4) * 32;
    int t = threadIdx.x;
    int w = t >> 6, lane = t & 63;
    int lr = lane & 15, quad = lane >> 4;

    m2l[t] = m2[b * NM + t];
    if (t < 32) n2l[t] = n2g[(size_t)b * NN + n0 + t];

    // ---- stage x1l [tok][c] (transpose during write) ----
    #pragma unroll
    for (int it = 0; it < 4; ++it) {
        int f4 = it * 256 + t;                  // < 1024
        int c = f4 >> 3, nn4 = (f4 & 7) * 4;
        float4 v = *(const float4*)&x[((size_t)b * NC + c) * NN + n0 + nn4];
        x1l[(nn4 + 0) * 132 + c] = v.x;
        x1l[(nn4 + 1) * 132 + c] = v.y;
        x1l[(nn4 + 2) * 132 + c] = v.z;
        x1l[(nn4 + 3) * 132 + c] = v.w;
    }
    __syncthreads();

    // ---- cooperative split-bf16 conversion of token planes (16 elems/thread) ----
    {
        int tok = t >> 3, c0 = (t & 7) * 16;
        #pragma unroll
        for (int g = 0; g < 4; ++g) {
            float4 v = *(const float4*)&x1l[tok * 132 + c0 + 4 * g];
            float vf[4] = {v.x, v.y, v.z, v.w};
            unsigned short h4[4], l4[4];
            #pragma unroll
            for (int e = 0; e < 4; ++e) {
                unsigned short h = bf16_rne(vf[e]);
                h4[e] = h;
                l4[e] = bf16_rne(vf[e] - __uint_as_float(((unsigned)h) << 16));
            }
            *(ushort4*)&xhp[tok * 136 + c0 + 4 * g] = make_ushort4(h4[0], h4[1], h4[2], h4[3]);
            *(ushort4*)&xlp[tok * 136 + c0 + 4 * g] = make_ushort4(l4[0], l4[1], l4[2], l4[3]);
        }
    }
    __syncthreads();

    // ---- MFMA: A = samples (global planes, batch-issued), B = tokens (LDS) ----
    // acc[h][j]: h = token half (cols 16h..16h+15), j = m-subtile.
    // Per-acc term order (AhBh, AhBl, AlBh) identical to prior versions.
    f32x4 acc[2][4];
    #pragma unroll
    for (int i = 0; i < 2; ++i)
        #pragma unroll
        for (int j = 0; j < 4; ++j) acc[i][j] = (f32x4){0.f, 0.f, 0.f, 0.f};
    int mbase = w * 64;
    #pragma unroll
    for (int kb = 0; kb < 4; ++kb) {
        int co = kb * 32 + quad * 8;
        bf16x8 Bh0 = *(const bf16x8*)&xhp[lr * 136 + co];
        bf16x8 Bl0 = *(const bf16x8*)&xlp[lr * 136 + co];
        bf16x8 Bh1 = *(const bf16x8*)&xhp[(16 + lr) * 136 + co];
        bf16x8 Bl1 = *(const bf16x8*)&xlp[(16 + lr) * 136 + co];
        bf16x8 Ah[4], Al[4];
        #pragma unroll
        for (int j = 0; j < 4; ++j) {               // batch-issue 8 global loads
            size_t arow = ((size_t)(b * NM + mbase + 16 * j + lr)) * NC + co;
            Ah[j] = *(const bf16x8*)&xsTh[arow];
            Al[j] = *(const bf16x8*)&xsTl[arow];
        }
        #pragma unroll
        for (int j = 0; j < 4; ++j) {
            acc[0][j] = __builtin_amdgcn_mfma_f32_16x16x32_bf16(Ah[j], Bh0, acc[0][j], 0, 0, 0);
            acc[0][j] = __builtin_amdgcn_mfma_f32_16x16x32_bf16(Ah[j], Bl0, acc[0][j], 0, 0, 0);
            acc[0][j] = __builtin_amdgcn_mfma_f32_16x16x32_bf16(Al[j], Bh0, acc[0][j], 0, 0, 0);
            acc[1][j] = __builtin_amdgcn_mfma_f32_16x16x32_bf16(Ah[j], Bh1, acc[1][j], 0, 0, 0);
            acc[1][j] = __builtin_amdgcn_mfma_f32_16x16x32_bf16(Ah[j], Bl1, acc[1][j], 0, 0, 0);
            acc[1][j] = __builtin_amdgcn_mfma_f32_16x16x32_bf16(Al[j], Bh1, acc[1][j], 0, 0, 0);
        }
    }

    // ---- per-half selection: sorted top-16 with index-carrying keys ----
    #pragma unroll
    for (int h = 0; h < 2; ++h) {
        unsigned s16v[16];
        #pragma unroll
        for (int j = 0; j < 4; ++j)
            #pragma unroll
            for (int r = 0; r < 4; ++r) {
                int m = mbase + 16 * j + quad * 4 + r;
                float key = fmaf(-2.f, acc[h][j][r], m2l[m]);
                unsigned u = __float_as_uint(key);
                u = (u & 0x80000000u) ? ~u : (u | 0x80000000u);
                s16v[4 * j + r] = (u & 0xFFFFFF00u) | (unsigned)m;
            }
        #define CE(i,jx) { unsigned a_ = s16v[i], b_ = s16v[jx]; s16v[i] = min(a_, b_); s16v[jx] = max(a_, b_); }
        // sort8 [0..7]
        CE(0,1) CE(2,3) CE(0,2) CE(1,3) CE(1,2)
        CE(4,5) CE(6,7) CE(4,6) CE(5,7) CE(5,6)
        CE(0,4) CE(2,6) CE(2,4) CE(1,5) CE(3,7) CE(3,5) CE(1,2) CE(3,4) CE(5,6)
        // sort8 [8..15]
        CE(8,9) CE(10,11) CE(8,10) CE(9,11) CE(9,10)
        CE(12,13) CE(14,15) CE(12,14) CE(13,15) CE(13,14)
        CE(8,12) CE(10,14) CE(10,12) CE(9,13) CE(11,15) CE(11,13) CE(9,10) CE(11,12) CE(13,14)
        // odd-even merge 8+8
        CE(0,8) CE(4,12) CE(4,8) CE(2,10) CE(6,14) CE(6,10) CE(2,4) CE(6,8) CE(10,12)
        CE(1,9) CE(5,13) CE(5,9) CE(3,11) CE(7,15) CE(7,11) CE(3,5) CE(7,9) CE(11,13)
        CE(1,2) CE(3,4) CE(5,6) CE(7,8) CE(9,10) CE(11,12) CE(13,14)
        #undef CE

        // butterfly across the 4 quads (token lr lives in lanes lr+16q)
        #pragma unroll
        for (int d = 16; d <= 32; d <<= 1) {
            unsigned q[16];
            #pragma unroll
            for (int i = 0; i < 16; ++i) q[i] = (unsigned)__shfl_xor((int)s16v[i], d, 64);
            merge16(s16v, q);
        }

        // cross-wave: publish once, merge other 3 waves' sorted lists
        if (quad == 0) {
            #pragma unroll
            for (int ii = 0; ii < 4; ++ii)
                *(uint4*)&wl[(w * 16 + lr) * 16 + 4 * ii] =
                    make_uint4(s16v[4*ii], s16v[4*ii+1], s16v[4*ii+2], s16v[4*ii+3]);
        }
        __syncthreads();
        #pragma unroll
        for (int p = 1; p < 4; ++p) {
            int pw = (w + p) & 3;
            unsigned q[16];
            #pragma unroll
            for (int i = 0; i < 16; ++i) q[i] = wl[(pw * 16 + lr) * 16 + i];
            merge16(s16v, q);
        }
        if (w == 0 && quad == 0) {
            unsigned* c32 = (unsigned*)candl;
            #pragma unroll
            for (int i = 0; i < 16; i += 2)
                c32[(16 * h + lr) * 8 + (i >> 1)] =
                    (s16v[i] & 255u) | ((s16v[i + 1] & 255u) << 16);
        }
        __syncthreads();   // protects wl reuse (h=0) / precedes pairs aliasing (h=1)
    }

    // ---- ref: np-bit-exact re-rank (32 tokens x 8 lanes x 2 slots) ----
    {
        int tok = t >> 3, q8 = t & 7;
        float n2 = n2l[tok];
        int mym[2];
        unsigned long long myp[2];
        #pragma unroll
        for (int s = 0; s < 2; ++s) {
            int m = candl[tok * 16 + q8 + 8 * s];
            mym[s] = m;
            const float* xt = xsT + ((size_t)(b * NM + m)) * NC;
            float dot = 0.f;
            for (int c4 = 0; c4 < 32; ++c4) {   // sequential in-order: np order
                float4 xv = *(const float4*)&x1l[tok * 132 + 4 * c4];
                float4 sv = *(const float4*)&xt[4 * c4];
                dot = __fadd_rn(dot, __fmul_rn(xv.x, sv.x));
                dot = __fadd_rn(dot, __fmul_rn(xv.y, sv.y));
                dot = __fadd_rn(dot, __fmul_rn(xv.z, sv.z));
                dot = __fadd_rn(dot, __fmul_rn(xv.w, sv.w));
            }
            float key = __fsub_rn(__fadd_rn(n2, m2l[m]), __fmul_rn(2.f, dot));
            unsigned u = __float_as_uint(key);
            u = (u & 0x80000000u) ? ~u : (u | 0x80000000u);
            myp[s] = ((unsigned long long)u << 32) | (unsigned)m;
            pairs[tok * 17 + q8 + 8 * s] = myp[s];
        }
        __syncthreads();
        unsigned long long pl[16];
        #pragma unroll
        for (int l2 = 0; l2 < 16; ++l2) pl[l2] = pairs[tok * 17 + l2];
        size_t obase = (size_t)(b * NN + n0 + tok) * NK;
        #pragma unroll
        for (int s = 0; s < 2; ++s) {
            int rank = 0;
            #pragma unroll
            for (int l2 = 0; l2 < 16; ++l2) rank += (pl[l2] < myp[s]);
            if (rank < 9) idx[obase + rank] = mym[s];
        }
    }
}

// ---------------------------------------------------------------------------
// K_OUT: out[b][o][n] = bias[o] + sum_k G[b][idx[b,n,k]][k][o]
__global__ __launch_bounds__(256) void k_out(const float* __restrict__ G,
                                             const int* __restrict__ idx,
                                             const float* __restrict__ bias,
                                             float* __restrict__ out) {
    __shared__ float S[64 * 129];
    __shared__ int   idxl[576];
    __shared__ float biasl[128];
    int b = blockIdx.x & 15, n0 = (blockIdx.x >> 4) * 64;
    int t = threadIdx.x;
    if (t < 128) biasl[t] = bias[t];
    for (int f = t; f < 576; f += 256) idxl[f] = idx[(size_t)(b * NN + n0) * NK + f];
    __syncthreads();
    int o = t & 127, half = t >> 7;
    for (int p = 0; p < 32; ++p) {
        int n = p * 2 + half;
        float a = biasl[o];
        #pragma unroll
        for (int k = 0; k < 9; ++k) {
            int m = idxl[n * 9 + k];
            a += G[(((size_t)(b * NM + m)) * NK + k) * 128 + o];
        }
        S[n * 129 + o] = a;
    }
    __syncthreads();
    int nn = t & 63, ob = t >> 6;
    for (int p = 0; p < 32; ++p) {
        int o2 = p * 4 + ob;
        out[((size_t)(b * NO + o2)) * NN + n0 + nn] = S[nn * 129 + o2];
    }
}

// ---------------------------------------------------------------------------
extern "C" void kernel_launch(void* const* d_in, const int* in_sizes, int n_in,
                              void* d_out, int out_size, void* d_ws, size_t ws_size,
                              hipStream_t stream) {
    const float* x    = (const float*)d_in[0];   // (16,128,64,64)
    const float* w    = (const float*)d_in[1];   // (128,128,9)
    const float* bias = (const float*)d_in[2];   // (128,)
    float* out = (float*)d_out;

    float* ws   = (float*)d_ws;
    float* m2   = ws;                            // 4096
    float* n2g  = ws + 4096;                     // 65536
    float* xsT  = ws + 69632;                    // 524288
    float* G    = ws + 593920;                   // 4718592
    int*   idx  = (int*)(ws + 5312512);          // 589824
    unsigned short* xsTh = (unsigned short*)(ws + 5902336);  // 524288 u16
    unsigned short* xsTl = (unsigned short*)(ws + 6164480);  // 524288 u16
    unsigned short* Wth  = (unsigned short*)(ws + 6426624);  // 147456 u16
    unsigned short* Wtl  = (unsigned short*)(ws + 6500352);  // 147456 u16

    k_prep  <<<dim3(976),  dim3(256), 0, stream>>>(x, w, xsT, xsTh, xsTl, Wth, Wtl, n2g, m2);
    k_g     <<<dim3(576),  dim3(256), 0, stream>>>(xsTh, xsTl, Wth, Wtl, G);
    k_selref<<<dim3(2048), dim3(256), 0, stream>>>(x, xsTh, xsTl, xsT, m2, n2g, idx);
    k_out   <<<dim3(1024), dim3(256), 0, stream>>>(G, idx, bias, out);
}

// Round 4
// 231.224 us; speedup vs baseline: 1.0884x; 1.0052x over previous
//
#include <hip/hip_runtime.h>

// Problem constants (B=16, C=128, H=W=64, N=4096, M=256, K=9, OUT=128)
#define NB   16
#define NC   128
#define NN   4096
#define NM   256
#define NK   9
#define NO   128

typedef __attribute__((ext_vector_type(8))) short bf16x8;
typedef __attribute__((ext_vector_type(4))) float f32x4;

__device__ __constant__ int d_grid16[16] = {0,4,8,13,17,21,25,29,34,38,42,46,50,55,59,63};

__device__ inline unsigned short bf16_rne(float v) {
    unsigned u = __float_as_uint(v);
    return (unsigned short)((u + 0x7FFFu + ((u >> 16) & 1u)) >> 16);
}

// Merge two ascending sorted 16-lists, keep lowest 16 ascending (branch-free).
// s := sorted16( lowest16( s ∪ q ) );  q must be ascending sorted.
__device__ inline void merge16(unsigned* s, const unsigned* q) {
    unsigned r[16];
    #pragma unroll
    for (int i = 0; i < 16; ++i) r[i] = min(s[i], q[15 - i]);   // bitonic low-half
    #pragma unroll
    for (int d = 8; d >= 1; d >>= 1)
        #pragma unroll
        for (int i = 0; i < 16; ++i)
            if (!(i & d)) { unsigned a = r[i], b2 = r[i + d]; r[i] = min(a, b2); r[i + d] = max(a, b2); }
    #pragma unroll
    for (int i = 0; i < 16; ++i) s[i] = r[i];
}

// ---------------------------------------------------------------------------
// K_PREP: unchanged (reduction loops unrolled 16; add-chain order preserved).
__global__ __launch_bounds__(256) void k_prep(const float* __restrict__ x,
                                              const float* __restrict__ w,
                                              float* __restrict__ xsT,
                                              unsigned short* __restrict__ xsTh,
                                              unsigned short* __restrict__ xsTl,
                                              unsigned short* __restrict__ Wth,
                                              unsigned short* __restrict__ Wtl,
                                              float* __restrict__ n2g,
                                              float* __restrict__ m2) {
    __shared__ float tile[16 * 260];
    int bx = blockIdx.x, t = threadIdx.x;
    if (bx < 128) {
        int b = bx >> 3, c0 = (bx & 7) * 16;
        int m = t;
        int pix = d_grid16[m >> 4] * 64 + d_grid16[m & 15];
        #pragma unroll
        for (int cc = 0; cc < 16; ++cc)
            tile[cc * 260 + m] = x[((size_t)b * NC + c0 + cc) * NN + pix];
        __syncthreads();
        #pragma unroll
        for (int e = 0; e < 4; ++e) {
            float fv[4];
            fv[0] = tile[(4 * e + 0) * 260 + m];
            fv[1] = tile[(4 * e + 1) * 260 + m];
            fv[2] = tile[(4 * e + 2) * 260 + m];
            fv[3] = tile[(4 * e + 3) * 260 + m];
            size_t base = ((size_t)b * NM + m) * NC + c0 + 4 * e;
            *(float4*)&xsT[base] = make_float4(fv[0], fv[1], fv[2], fv[3]);
            unsigned short h4[4], l4[4];
            #pragma unroll
            for (int e2 = 0; e2 < 4; ++e2) {
                unsigned short h = bf16_rne(fv[e2]);
                h4[e2] = h;
                l4[e2] = bf16_rne(fv[e2] - __uint_as_float(((unsigned)h) << 16));
            }
            *(ushort4*)&xsTh[base] = make_ushort4(h4[0], h4[1], h4[2], h4[3]);
            *(ushort4*)&xsTl[base] = make_ushort4(l4[0], l4[1], l4[2], l4[3]);
        }
    } else if (bx < 704) {
        int f = (bx - 128) * 256 + t;               // < 147456 = 1152*128
        int ko = f >> 7, c = f & 127;
        int o = ko & 127, k = ko >> 7;
        float v = w[(size_t)o * 1152 + c * 9 + k];
        unsigned short h = bf16_rne(v);
        Wth[f] = h;
        Wtl[f] = bf16_rne(v - __uint_as_float(((unsigned)h) << 16));
    } else if (bx < 960) {
        #pragma clang fp contract(off)
        int i = bx - 704;                           // 256 blocks: b x 16 n-chunks
        int b = i >> 4, n = (i & 15) * 256 + t;
        const float* p = x + (size_t)b * NC * NN + n;
        float a = 0.f;
        #pragma unroll 16
        for (int c = 0; c < NC; ++c) { float v = p[(size_t)c * NN]; a = __fadd_rn(a, __fmul_rn(v, v)); }
        n2g[(size_t)b * NN + n] = a;
    } else {
        #pragma clang fp contract(off)
        int b = bx - 960;                           // 16 blocks: t = m
        int pix = d_grid16[t >> 4] * 64 + d_grid16[t & 15];
        const float* p = x + (size_t)b * NC * NN + pix;
        float a = 0.f;
        #pragma unroll 16
        for (int c = 0; c < NC; ++c) { float v = p[(size_t)c * NN]; a = __fadd_rn(a, __fmul_rn(v, v)); }
        m2[b * NM + t] = a;
    }
}

// ---------------------------------------------------------------------------
// K_G (MFMA): G[b][m][k][o] = sum_c xs[m][c] * W[k,o][c], split-bf16 3-term.
__global__ __launch_bounds__(256) void k_g(const unsigned short* __restrict__ xsTh,
                                           const unsigned short* __restrict__ xsTl,
                                           const unsigned short* __restrict__ Wth,
                                           const unsigned short* __restrict__ Wtl,
                                           float* __restrict__ G) {
    int id = blockIdx.x;
    int b = id & 15, r = id >> 4;                   // r < 36
    int kk = r % 9, mt = r / 9;
    int t = threadIdx.x;
    int w = t >> 6, lane = t & 63;
    int lr = lane & 15, quad = lane >> 4;
    int m = b * NM + mt * 64 + w * 16 + lr;
    const unsigned short* aph = xsTh + (size_t)m * NC;
    const unsigned short* apl = xsTl + (size_t)m * NC;
    f32x4 acc[8];
    #pragma unroll
    for (int j = 0; j < 8; ++j) acc[j] = (f32x4){0.f, 0.f, 0.f, 0.f};
    #pragma unroll
    for (int kb = 0; kb < 4; ++kb) {
        int co = kb * 32 + quad * 8;
        bf16x8 Ah = *(const bf16x8*)&aph[co];
        bf16x8 Al = *(const bf16x8*)&apl[co];
        #pragma unroll
        for (int j = 0; j < 8; ++j) {
            size_t wrow = ((size_t)kk * 128 + 16 * j + lr) * NC + co;
            bf16x8 Bh = *(const bf16x8*)&Wth[wrow];
            bf16x8 Bl = *(const bf16x8*)&Wtl[wrow];
            acc[j] = __builtin_amdgcn_mfma_f32_16x16x32_bf16(Ah, Bh, acc[j], 0, 0, 0);
            acc[j] = __builtin_amdgcn_mfma_f32_16x16x32_bf16(Al, Bh, acc[j], 0, 0, 0);
            acc[j] = __builtin_amdgcn_mfma_f32_16x16x32_bf16(Ah, Bl, acc[j], 0, 0, 0);
        }
    }
    int mrow = b * NM + mt * 64 + w * 16 + quad * 4;
    #pragma unroll
    for (int j = 0; j < 8; ++j)
        #pragma unroll
        for (int r2 = 0; r2 < 4; ++r2)
            G[((size_t)(mrow + r2)) * 1152 + kk * 128 + 16 * j + lr] = acc[j][r2];
}

// ---------------------------------------------------------------------------
// K_SELREF v5: same algorithm as v4 but restructured for occupancy + latency:
//  - no x1l f32 buffer: bf16 planes converted directly from staging registers
//    (bit-identical values); after selection, x f32 is re-staged from L2 into
//    the then-dead plane region (union) for the np-exact re-rank.
//    LDS 40.0 KB -> 23.9 KB => 6 blocks/CU (VGPR ~80 allows 6 waves/SIMD).
//  - cross-wave merge runs on wave 0 only (results of other waves' merges
//    were never consumed); waves 1-3 reach the barrier ~480 ops earlier.
__global__ __launch_bounds__(256, 2) void k_selref(const float* __restrict__ x,
                                                   const unsigned short* __restrict__ xsTh,
                                                   const unsigned short* __restrict__ xsTl,
                                                   const float* __restrict__ xsT,
                                                   const float* __restrict__ m2,
                                                   const float* __restrict__ n2g,
                                                   int* __restrict__ idx) {
    #pragma clang fp contract(off)
    __shared__ __align__(16) unsigned char ubuf[17408];      // planes ∪ xr
    __shared__ __align__(16) unsigned mrg[1088];             // 4352 B: wl ∪ pairs
    __shared__ unsigned short candl[32 * 16];                // 1024 B
    __shared__ float m2l[256];                               // 1024 B
    __shared__ float n2l[32];                                //  128 B
    unsigned short* xhp = (unsigned short*)ubuf;             // [32][136] bf16-hi
    unsigned short* xlp = xhp + 32 * 136;                    // [32][136] bf16-lo
    float* xr = (float*)ubuf;                                // [32][132] f32 (re-rank)
    unsigned* wl = mrg;                                      // [wave][lr][16] u32
    unsigned long long* pairs = (unsigned long long*)mrg;    // [tok][17] u64

    int b = blockIdx.x & 15, n0 = (blockIdx.x >> 4) * 32;
    int t = threadIdx.x;
    int w = t >> 6, lane = t & 63;
    int lr = lane & 15, quad = lane >> 4;

    m2l[t] = m2[b * NM + t];
    if (t < 32) n2l[t] = n2g[(size_t)b * NN + n0 + t];

    // ---- stage + split-bf16 convert directly into LDS planes ----
    #pragma unroll
    for (int it = 0; it < 4; ++it) {
        int f4 = it * 256 + t;                  // < 1024
        int c = f4 >> 3, nn4 = (f4 & 7) * 4;
        float4 v = *(const float4*)&x[((size_t)b * NC + c) * NN + n0 + nn4];
        float vf[4] = {v.x, v.y, v.z, v.w};
        #pragma unroll
        for (int e = 0; e < 4; ++e) {
            unsigned short h = bf16_rne(vf[e]);
            unsigned short l = bf16_rne(vf[e] - __uint_as_float(((unsigned)h) << 16));
            xhp[(nn4 + e) * 136 + c] = h;
            xlp[(nn4 + e) * 136 + c] = l;
        }
    }
    __syncthreads();

    // ---- MFMA: A = samples (global planes, batch-issued), B = tokens (LDS) ----
    // acc[h][j]: h = token half (cols 16h..16h+15), j = m-subtile.
    // Per-acc term order (AhBh, AhBl, AlBh) identical to prior versions.
    f32x4 acc[2][4];
    #pragma unroll
    for (int i = 0; i < 2; ++i)
        #pragma unroll
        for (int j = 0; j < 4; ++j) acc[i][j] = (f32x4){0.f, 0.f, 0.f, 0.f};
    int mbase = w * 64;
    #pragma unroll
    for (int kb = 0; kb < 4; ++kb) {
        int co = kb * 32 + quad * 8;
        bf16x8 Bh0 = *(const bf16x8*)&xhp[lr * 136 + co];
        bf16x8 Bl0 = *(const bf16x8*)&xlp[lr * 136 + co];
        bf16x8 Bh1 = *(const bf16x8*)&xhp[(16 + lr) * 136 + co];
        bf16x8 Bl1 = *(const bf16x8*)&xlp[(16 + lr) * 136 + co];
        bf16x8 Ah[4], Al[4];
        #pragma unroll
        for (int j = 0; j < 4; ++j) {               // batch-issue 8 global loads
            size_t arow = ((size_t)(b * NM + mbase + 16 * j + lr)) * NC + co;
            Ah[j] = *(const bf16x8*)&xsTh[arow];
            Al[j] = *(const bf16x8*)&xsTl[arow];
        }
        #pragma unroll
        for (int j = 0; j < 4; ++j) {
            acc[0][j] = __builtin_amdgcn_mfma_f32_16x16x32_bf16(Ah[j], Bh0, acc[0][j], 0, 0, 0);
            acc[0][j] = __builtin_amdgcn_mfma_f32_16x16x32_bf16(Ah[j], Bl0, acc[0][j], 0, 0, 0);
            acc[0][j] = __builtin_amdgcn_mfma_f32_16x16x32_bf16(Al[j], Bh0, acc[0][j], 0, 0, 0);
            acc[1][j] = __builtin_amdgcn_mfma_f32_16x16x32_bf16(Ah[j], Bh1, acc[1][j], 0, 0, 0);
            acc[1][j] = __builtin_amdgcn_mfma_f32_16x16x32_bf16(Ah[j], Bl1, acc[1][j], 0, 0, 0);
            acc[1][j] = __builtin_amdgcn_mfma_f32_16x16x32_bf16(Al[j], Bh1, acc[1][j], 0, 0, 0);
        }
    }

    // ---- per-half selection: sorted top-16 with index-carrying keys ----
    #pragma unroll
    for (int h = 0; h < 2; ++h) {
        unsigned s16v[16];
        #pragma unroll
        for (int j = 0; j < 4; ++j)
            #pragma unroll
            for (int r = 0; r < 4; ++r) {
                int m = mbase + 16 * j + quad * 4 + r;
                float key = fmaf(-2.f, acc[h][j][r], m2l[m]);
                unsigned u = __float_as_uint(key);
                u = (u & 0x80000000u) ? ~u : (u | 0x80000000u);
                s16v[4 * j + r] = (u & 0xFFFFFF00u) | (unsigned)m;
            }
        #define CE(i,jx) { unsigned a_ = s16v[i], b_ = s16v[jx]; s16v[i] = min(a_, b_); s16v[jx] = max(a_, b_); }
        // sort8 [0..7]
        CE(0,1) CE(2,3) CE(0,2) CE(1,3) CE(1,2)
        CE(4,5) CE(6,7) CE(4,6) CE(5,7) CE(5,6)
        CE(0,4) CE(2,6) CE(2,4) CE(1,5) CE(3,7) CE(3,5) CE(1,2) CE(3,4) CE(5,6)
        // sort8 [8..15]
        CE(8,9) CE(10,11) CE(8,10) CE(9,11) CE(9,10)
        CE(12,13) CE(14,15) CE(12,14) CE(13,15) CE(13,14)
        CE(8,12) CE(10,14) CE(10,12) CE(9,13) CE(11,15) CE(11,13) CE(9,10) CE(11,12) CE(13,14)
        // odd-even merge 8+8
        CE(0,8) CE(4,12) CE(4,8) CE(2,10) CE(6,14) CE(6,10) CE(2,4) CE(6,8) CE(10,12)
        CE(1,9) CE(5,13) CE(5,9) CE(3,11) CE(7,15) CE(7,11) CE(3,5) CE(7,9) CE(11,13)
        CE(1,2) CE(3,4) CE(5,6) CE(7,8) CE(9,10) CE(11,12) CE(13,14)
        #undef CE

        // butterfly across the 4 quads (token lr lives in lanes lr+16q)
        #pragma unroll
        for (int d = 16; d <= 32; d <<= 1) {
            unsigned q[16];
            #pragma unroll
            for (int i = 0; i < 16; ++i) q[i] = (unsigned)__shfl_xor((int)s16v[i], d, 64);
            merge16(s16v, q);
        }

        // publish per-wave list; wave 0 merges waves 1..3 and emits candidates
        if (quad == 0) {
            #pragma unroll
            for (int ii = 0; ii < 4; ++ii)
                *(uint4*)&wl[(w * 16 + lr) * 16 + 4 * ii] =
                    make_uint4(s16v[4*ii], s16v[4*ii+1], s16v[4*ii+2], s16v[4*ii+3]);
        }
        __syncthreads();
        if (w == 0) {
            #pragma unroll
            for (int p = 1; p < 4; ++p) {
                unsigned q[16];
                #pragma unroll
                for (int i = 0; i < 16; ++i) q[i] = wl[(p * 16 + lr) * 16 + i];
                merge16(s16v, q);
            }
            if (quad == 0) {
                unsigned* c32 = (unsigned*)candl;
                #pragma unroll
                for (int i = 0; i < 16; i += 2)
                    c32[(16 * h + lr) * 8 + (i >> 1)] =
                        (s16v[i] & 255u) | ((s16v[i + 1] & 255u) << 16);
            }
        }
        __syncthreads();   // protects wl reuse (h=0) / precedes ubuf+mrg reuse (h=1)
    }

    // ---- re-stage x f32 into the dead plane region for the exact re-rank ----
    #pragma unroll
    for (int it = 0; it < 4; ++it) {
        int f4 = it * 256 + t;
        int c = f4 >> 3, nn4 = (f4 & 7) * 4;
        float4 v = *(const float4*)&x[((size_t)b * NC + c) * NN + n0 + nn4];
        xr[(nn4 + 0) * 132 + c] = v.x;
        xr[(nn4 + 1) * 132 + c] = v.y;
        xr[(nn4 + 2) * 132 + c] = v.z;
        xr[(nn4 + 3) * 132 + c] = v.w;
    }
    __syncthreads();

    // ---- ref: np-bit-exact re-rank (32 tokens x 8 lanes x 2 slots) ----
    {
        int tok = t >> 3, q8 = t & 7;
        float n2 = n2l[tok];
        int mym[2];
        unsigned long long myp[2];
        #pragma unroll
        for (int s = 0; s < 2; ++s) {
            int m = candl[tok * 16 + q8 + 8 * s];
            mym[s] = m;
            const float* xt = xsT + ((size_t)(b * NM + m)) * NC;
            float dot = 0.f;
            for (int c4 = 0; c4 < 32; ++c4) {   // sequential in-order: np order
                float4 xv = *(const float4*)&xr[tok * 132 + 4 * c4];
                float4 sv = *(const float4*)&xt[4 * c4];
                dot = __fadd_rn(dot, __fmul_rn(xv.x, sv.x));
                dot = __fadd_rn(dot, __fmul_rn(xv.y, sv.y));
                dot = __fadd_rn(dot, __fmul_rn(xv.z, sv.z));
                dot = __fadd_rn(dot, __fmul_rn(xv.w, sv.w));
            }
            float key = __fsub_rn(__fadd_rn(n2, m2l[m]), __fmul_rn(2.f, dot));
            unsigned u = __float_as_uint(key);
            u = (u & 0x80000000u) ? ~u : (u | 0x80000000u);
            myp[s] = ((unsigned long long)u << 32) | (unsigned)m;
            pairs[tok * 17 + q8 + 8 * s] = myp[s];
        }
        __syncthreads();
        unsigned long long pl[16];
        #pragma unroll
        for (int l2 = 0; l2 < 16; ++l2) pl[l2] = pairs[tok * 17 + l2];
        size_t obase = (size_t)(b * NN + n0 + tok) * NK;
        #pragma unroll
        for (int s = 0; s < 2; ++s) {
            int rank = 0;
            #pragma unroll
            for (int l2 = 0; l2 < 16; ++l2) rank += (pl[l2] < myp[s]);
            if (rank < 9) idx[obase + rank] = mym[s];
        }
    }
}

// ---------------------------------------------------------------------------
// K_OUT: out[b][o][n] = bias[o] + sum_k G[b][idx[b,n,k]][k][o]
__global__ __launch_bounds__(256) void k_out(const float* __restrict__ G,
                                             const int* __restrict__ idx,
                                             const float* __restrict__ bias,
                                             float* __restrict__ out) {
    __shared__ float S[64 * 129];
    __shared__ int   idxl[576];
    __shared__ float biasl[128];
    int b = blockIdx.x & 15, n0 = (blockIdx.x >> 4) * 64;
    int t = threadIdx.x;
    if (t < 128) biasl[t] = bias[t];
    for (int f = t; f < 576; f += 256) idxl[f] = idx[(size_t)(b * NN + n0) * NK + f];
    __syncthreads();
    int o = t & 127, half = t >> 7;
    for (int p = 0; p < 32; ++p) {
        int n = p * 2 + half;
        float a = biasl[o];
        #pragma unroll
        for (int k = 0; k < 9; ++k) {
            int m = idxl[n * 9 + k];
            a += G[(((size_t)(b * NM + m)) * NK + k) * 128 + o];
        }
        S[n * 129 + o] = a;
    }
    __syncthreads();
    int nn = t & 63, ob = t >> 6;
    for (int p = 0; p < 32; ++p) {
        int o2 = p * 4 + ob;
        out[((size_t)(b * NO + o2)) * NN + n0 + nn] = S[nn * 129 + o2];
    }
}

// ---------------------------------------------------------------------------
extern "C" void kernel_launch(void* const* d_in, const int* in_sizes, int n_in,
                              void* d_out, int out_size, void* d_ws, size_t ws_size,
                              hipStream_t stream) {
    const float* x    = (const float*)d_in[0];   // (16,128,64,64)
    const float* w    = (const float*)d_in[1];   // (128,128,9)
    const float* bias = (const float*)d_in[2];   // (128,)
    float* out = (float*)d_out;

    float* ws   = (float*)d_ws;
    float* m2   = ws;                            // 4096
    float* n2g  = ws + 4096;                     // 65536
    float* xsT  = ws + 69632;                    // 524288
    float* G    = ws + 593920;                   // 4718592
    int*   idx  = (int*)(ws + 5312512);          // 589824
    unsigned short* xsTh = (unsigned short*)(ws + 5902336);  // 524288 u16
    unsigned short* xsTl = (unsigned short*)(ws + 6164480);  // 524288 u16
    unsigned short* Wth  = (unsigned short*)(ws + 6426624);  // 147456 u16
    unsigned short* Wtl  = (unsigned short*)(ws + 6500352);  // 147456 u16

    k_prep  <<<dim3(976),  dim3(256), 0, stream>>>(x, w, xsT, xsTh, xsTl, Wth, Wtl, n2g, m2);
    k_g     <<<dim3(576),  dim3(256), 0, stream>>>(xsTh, xsTl, Wth, Wtl, G);
    k_selref<<<dim3(2048), dim3(256), 0, stream>>>(x, xsTh, xsTl, xsT, m2, n2g, idx);
    k_out   <<<dim3(1024), dim3(256), 0, stream>>>(G, idx, bias, out);
}